// Round 2
// baseline (222.334 us; speedup 1.0000x reference)
//
#include <hip/hip_runtime.h>

#define TT 8192
#define CC 512

typedef unsigned short u16;
typedef unsigned int u32;
typedef __attribute__((ext_vector_type(8))) short bf16x8;
typedef __attribute__((ext_vector_type(4))) float f32x4;

__device__ __forceinline__ u16 f2bf(float f) {
    u32 u = __float_as_uint(f);
    return (u16)((u + 0x7FFFu + ((u >> 16) & 1u)) >> 16);
}

// ---------------- Kernel 1: LayerNorm -> xx (bf16) ----------------
__global__ void ln_kernel(const float* __restrict__ x,
                          const float* __restrict__ scale,
                          const float* __restrict__ bias,
                          u16* __restrict__ xx) {
    int row = blockIdx.x * 4 + (threadIdx.x >> 6);
    int l = threadIdx.x & 63;
    const float4* xr = (const float4*)(x + (size_t)row * CC);
    float4 a = xr[l * 2], b = xr[l * 2 + 1];
    float s = a.x + a.y + a.z + a.w + b.x + b.y + b.z + b.w;
    float q = a.x*a.x + a.y*a.y + a.z*a.z + a.w*a.w
            + b.x*b.x + b.y*b.y + b.z*b.z + b.w*b.w;
    #pragma unroll
    for (int m = 1; m < 64; m <<= 1) {
        s += __shfl_xor(s, m, 64);
        q += __shfl_xor(q, m, 64);
    }
    float mu = s * (1.0f / CC);
    float var = q * (1.0f / CC) - mu * mu;
    float rs = rsqrtf(var + 1e-5f);
    const float4* sc4 = (const float4*)scale;
    const float4* bi4 = (const float4*)bias;
    float4 s1 = sc4[l * 2], s2 = sc4[l * 2 + 1];
    float4 b1 = bi4[l * 2], b2 = bi4[l * 2 + 1];
    bf16x8 o;
    o[0] = (short)f2bf((a.x - mu) * rs * s1.x + b1.x);
    o[1] = (short)f2bf((a.y - mu) * rs * s1.y + b1.y);
    o[2] = (short)f2bf((a.z - mu) * rs * s1.z + b1.z);
    o[3] = (short)f2bf((a.w - mu) * rs * s1.w + b1.w);
    o[4] = (short)f2bf((b.x - mu) * rs * s2.x + b2.x);
    o[5] = (short)f2bf((b.y - mu) * rs * s2.y + b2.y);
    o[6] = (short)f2bf((b.z - mu) * rs * s2.z + b2.z);
    o[7] = (short)f2bf((b.w - mu) * rs * s2.w + b2.w);
    *(bf16x8*)(xx + (size_t)row * CC + l * 8) = o;
}

// ---------- Kernel 2: weight transposes -> WqkT [128][512], WvT [512][512] (bf16) ----------
__global__ void wtrans_kernel(const float* __restrict__ Wq,
                              const float* __restrict__ Wk,
                              const float* __restrict__ Wv,
                              u16* __restrict__ wqkt,
                              u16* __restrict__ wvt) {
    int tid = blockIdx.x * 256 + threadIdx.x;   // 0 .. 327679
    if (tid < 65536) {
        int c = tid >> 9, k = tid & 511;
        float w = (c < 64) ? Wq[k * 64 + c] : Wk[k * 64 + (c - 64)];
        wqkt[tid] = f2bf(w);
    } else {
        int i = tid - 65536;
        int c = i >> 9, k = i & 511;
        wvt[i] = f2bf(Wv[k * 512 + c]);
    }
}

// ---------- Kernel 3: qk = xx @ [Wq|Wk], q scaled by 1/8 -> qk bf16 [T][128] ----------
__global__ __launch_bounds__(256) void qk_gemm_kernel(const u16* __restrict__ xx,
                                                      const u16* __restrict__ wqkt,
                                                      u16* __restrict__ qk) {
    int w = threadIdx.x >> 6;
    int l = threadIdx.x & 63;
    int l15 = l & 15, g = l >> 4;
    int r0 = blockIdx.x * 64 + w * 16;

    f32x4 acc[8];
    #pragma unroll
    for (int i = 0; i < 8; ++i) acc[i] = (f32x4){0.f, 0.f, 0.f, 0.f};

    for (int kk = 0; kk < 16; ++kk) {
        int k = kk * 32 + g * 8;
        bf16x8 af = *(const bf16x8*)(xx + (r0 + l15) * CC + k);
        #pragma unroll
        for (int Nt = 0; Nt < 8; ++Nt) {
            int c = Nt * 16 + l15;
            bf16x8 bfr = *(const bf16x8*)(wqkt + c * CC + k);
            acc[Nt] = __builtin_amdgcn_mfma_f32_16x16x32_bf16(af, bfr, acc[Nt], 0, 0, 0);
        }
    }
    #pragma unroll
    for (int Nt = 0; Nt < 8; ++Nt) {
        int c = Nt * 16 + l15;
        float scl = (c < 64) ? 0.125f : 1.0f;
        #pragma unroll
        for (int jj = 0; jj < 4; ++jj) {
            int rg = r0 + g * 4 + jj;
            qk[rg * 128 + c] = f2bf(acc[Nt][jj] * scl);
        }
    }
}

// ---------- Kernel 4: v = x_emb @ Wv -> v bf16 [T][512] ----------
__global__ __launch_bounds__(256) void v_gemm_kernel(const float* __restrict__ xe,
                                                     const u16* __restrict__ wvt,
                                                     u16* __restrict__ v) {
    int w = threadIdx.x >> 6;
    int l = threadIdx.x & 63;
    int l15 = l & 15, g = l >> 4;
    int bm = blockIdx.x >> 2, bn = blockIdx.x & 3;
    int r0 = bm * 64 + w * 16;
    int c0 = bn * 128;

    f32x4 acc[8];
    #pragma unroll
    for (int i = 0; i < 8; ++i) acc[i] = (f32x4){0.f, 0.f, 0.f, 0.f};

    for (int kk = 0; kk < 16; ++kk) {
        int k = kk * 32 + g * 8;
        const float4* ap = (const float4*)(xe + (size_t)(r0 + l15) * CC + k);
        float4 a1 = ap[0], a2 = ap[1];
        bf16x8 af;
        af[0] = (short)f2bf(a1.x); af[1] = (short)f2bf(a1.y);
        af[2] = (short)f2bf(a1.z); af[3] = (short)f2bf(a1.w);
        af[4] = (short)f2bf(a2.x); af[5] = (short)f2bf(a2.y);
        af[6] = (short)f2bf(a2.z); af[7] = (short)f2bf(a2.w);
        #pragma unroll
        for (int Nt = 0; Nt < 8; ++Nt) {
            int c = c0 + Nt * 16 + l15;
            bf16x8 bfr = *(const bf16x8*)(wvt + c * CC + k);
            acc[Nt] = __builtin_amdgcn_mfma_f32_16x16x32_bf16(af, bfr, acc[Nt], 0, 0, 0);
        }
    }
    #pragma unroll
    for (int Nt = 0; Nt < 8; ++Nt) {
        int c = c0 + Nt * 16 + l15;
        #pragma unroll
        for (int jj = 0; jj < 4; ++jj) {
            int rg = r0 + g * 4 + jj;
            v[rg * CC + c] = f2bf(acc[Nt][jj]);
        }
    }
}

// ---------- Kernel 5: transpose v -> vT bf16 [512][T] ----------
__global__ void vtrans_kernel(const u16* __restrict__ v, u16* __restrict__ vt) {
    __shared__ u16 tl[64][72];
    int tr = blockIdx.x >> 3, tc = blockIdx.x & 7;
    int t = threadIdx.x;
    #pragma unroll
    for (int ii = 0; ii < 2; ++ii) {
        int slot = ii * 256 + t;
        int r = slot >> 3, c8 = slot & 7;
        *(bf16x8*)&tl[r][c8 * 8] =
            *(const bf16x8*)(v + (tr * 64 + r) * CC + tc * 64 + c8 * 8);
    }
    __syncthreads();
    #pragma unroll
    for (int ii = 0; ii < 2; ++ii) {
        int slot = ii * 256 + t;
        int c = slot >> 3, r8 = slot & 7;
        bf16x8 tv;
        #pragma unroll
        for (int jj = 0; jj < 8; ++jj) tv[jj] = (short)tl[r8 * 8 + jj][c];
        *(bf16x8*)(vt + (tc * 64 + c) * TT + tr * 64 + r8 * 8) = tv;
    }
}

// ---------- Kernel 6: flash (causal QK^T -> mask -> PV), partial O per s-chunk ----------
__global__ __launch_bounds__(256, 2) void flash_kernel(const u16* __restrict__ qk,
                                                       const u16* __restrict__ vt,
                                                       float* __restrict__ part,
                                                       int nc) {
    __shared__ u16 Klds[64 * 64];   // [s][a], XOR-swizzled 16B slots
    __shared__ u16 Slds[64 * 64];   // [r][s], XOR-swizzled 16B slots

    const int tid = threadIdx.x;
    const int w = tid >> 6;
    const int l = tid & 63;
    const int l15 = l & 15;
    const int g = l >> 4;

    const int b = blockIdx.x;
    const int rt = 127 - (b / nc);       // row-tile, big work first
    const int ch = b % nc;
    const int n = rt + 1;
    const int t_lo = (ch * n) / nc;
    const int t_hi = ((ch + 1) * n) / nc;

    // Q fragments (rows w*16 .. w*16+15 of this row-tile), already scaled by 1/8
    const int qrow = rt * 64 + w * 16 + l15;
    bf16x8 qf0 = *(const bf16x8*)(qk + qrow * 128 + g * 8);
    bf16x8 qf1 = *(const bf16x8*)(qk + qrow * 128 + 32 + g * 8);

    f32x4 acc[4][8];                     // O[64 rows][w*128 + Nt*16 cols]
    #pragma unroll
    for (int m = 0; m < 4; ++m)
        #pragma unroll
        for (int nn = 0; nn < 8; ++nn) acc[m][nn] = (f32x4){0.f, 0.f, 0.f, 0.f};

    for (int j = t_lo; j < t_hi; ++j) {
        const int s0 = j * 64;

        // stage K tile [64 s][64 a] (cols 64..127 of qk), swizzled: phys slot p holds logical p^(s&7)
        #pragma unroll
        for (int ii = 0; ii < 2; ++ii) {
            int slot = ii * 256 + tid;       // 0..511
            int sI = slot >> 3, p = slot & 7;
            int a8 = ((p ^ (sI & 7)) << 3);
            *(bf16x8*)&Klds[sI * 64 + p * 8] =
                *(const bf16x8*)(qk + (s0 + sI) * 128 + 64 + a8);
        }
        __syncthreads();

        // QK^T: wave w computes S rows [w*16, w*16+16)
        f32x4 sacc[4];
        #pragma unroll
        for (int Nt = 0; Nt < 4; ++Nt) sacc[Nt] = (f32x4){0.f, 0.f, 0.f, 0.f};
        #pragma unroll
        for (int Nt = 0; Nt < 4; ++Nt) {
            int srow = Nt * 16 + l15;
            #pragma unroll
            for (int ka = 0; ka < 2; ++ka) {
                int slot = (ka * 4 + g) ^ (srow & 7);
                bf16x8 kf = *(const bf16x8*)&Klds[srow * 64 + slot * 8];
                sacc[Nt] = __builtin_amdgcn_mfma_f32_16x16x32_bf16(
                    (ka == 0) ? qf0 : qf1, kf, sacc[Nt], 0, 0, 0);
            }
        }

        // mask (diag tile only) + convert + write S to swizzled LDS
        const bool diag = (j == rt);
        #pragma unroll
        for (int Nt = 0; Nt < 4; ++Nt) {
            int scol = Nt * 16 + l15;
            int sg = s0 + scol;
            #pragma unroll
            for (int jj = 0; jj < 4; ++jj) {
                int row = w * 16 + g * 4 + jj;
                float val = sacc[Nt][jj];
                if (diag && sg > rt * 64 + row) val = 0.f;
                int sc_hi = scol >> 3, sc_lo = scol & 7;
                Slds[row * 64 + (((sc_hi ^ (row & 7)) << 3) + sc_lo)] = f2bf(val);
            }
        }
        __syncthreads();

        // PV: A = S (all 64 rows) from LDS, B = vT columns [w*128, w*128+128)
        bf16x8 sf[4][2];
        #pragma unroll
        for (int Mt = 0; Mt < 4; ++Mt) {
            int row = Mt * 16 + l15;
            #pragma unroll
            for (int ka = 0; ka < 2; ++ka) {
                int slot = (ka * 4 + g) ^ (row & 7);
                sf[Mt][ka] = *(const bf16x8*)&Slds[row * 64 + slot * 8];
            }
        }
        #pragma unroll
        for (int Nt = 0; Nt < 8; ++Nt) {
            int c = w * 128 + Nt * 16 + l15;
            #pragma unroll
            for (int ka = 0; ka < 2; ++ka) {
                bf16x8 vf = *(const bf16x8*)(vt + c * TT + s0 + ka * 32 + g * 8);
                #pragma unroll
                for (int Mt = 0; Mt < 4; ++Mt)
                    acc[Mt][Nt] = __builtin_amdgcn_mfma_f32_16x16x32_bf16(
                        sf[Mt][ka], vf, acc[Mt][Nt], 0, 0, 0);
            }
        }
    }

    // write partial O (always, even if empty range — ws is poisoned)
    float* pb = part + (size_t)ch * ((size_t)TT * CC);
    #pragma unroll
    for (int Mt = 0; Mt < 4; ++Mt) {
        #pragma unroll
        for (int Nt = 0; Nt < 8; ++Nt) {
            int col = w * 128 + Nt * 16 + l15;
            #pragma unroll
            for (int jj = 0; jj < 4; ++jj) {
                int rg = rt * 64 + Mt * 16 + g * 4 + jj;
                pb[(size_t)rg * CC + col] = acc[Mt][Nt][jj];
            }
        }
    }
}

// ---------- Kernel 7: out = x + sum(partials) ----------
__global__ void combine_kernel(const float* __restrict__ x,
                               const float* __restrict__ part,
                               float* __restrict__ out, int nc) {
    int i = blockIdx.x * 256 + threadIdx.x;   // float4 index, 1048576 total
    const float4* x4 = (const float4*)x;
    const float4* p4 = (const float4*)part;
    float4 r = x4[i];
    for (int c = 0; c < nc; ++c) {
        float4 p = p4[(size_t)c * 1048576 + i];
        r.x += p.x; r.y += p.y; r.z += p.z; r.w += p.w;
    }
    ((float4*)out)[i] = r;
}

extern "C" void kernel_launch(void* const* d_in, const int* in_sizes, int n_in,
                              void* d_out, int out_size, void* d_ws, size_t ws_size,
                              hipStream_t stream) {
    (void)in_sizes; (void)n_in; (void)out_size;
    const float* x    = (const float*)d_in[0];
    const float* xe   = (const float*)d_in[1];
    const float* lns  = (const float*)d_in[2];
    const float* lnb  = (const float*)d_in[3];
    const float* Wq   = (const float*)d_in[4];
    const float* Wk   = (const float*)d_in[5];
    const float* Wv   = (const float*)d_in[6];
    float* out = (float*)d_out;
    char* ws = (char*)d_ws;

    size_t off_xx   = 0;                          // bf16 [8192][512]  8 MB
    size_t off_qk   = off_xx   + (size_t)TT * CC * 2;     // bf16 [8192][128]  2 MB
    size_t off_wqkt = off_qk   + (size_t)TT * 128 * 2;    // bf16 [128][512]
    size_t off_wvt  = off_wqkt + (size_t)128 * 512 * 2;   // bf16 [512][512]
    size_t off_v    = off_wvt  + (size_t)512 * 512 * 2;   // bf16 [8192][512]  8 MB
    size_t off_vt   = off_v    + (size_t)TT * CC * 2;     // bf16 [512][8192]  8 MB
    size_t off_part = off_vt   + (size_t)TT * CC * 2;     // f32 x nc x 16 MB

    int nc = 4;
    while (nc > 1 && off_part + (size_t)nc * ((size_t)TT * CC * 4) > ws_size) nc >>= 1;

    u16* xx   = (u16*)(ws + off_xx);
    u16* qk   = (u16*)(ws + off_qk);
    u16* wqkt = (u16*)(ws + off_wqkt);
    u16* wvt  = (u16*)(ws + off_wvt);
    u16* v    = (u16*)(ws + off_v);
    u16* vt   = (u16*)(ws + off_vt);
    float* part = (float*)(ws + off_part);

    hipLaunchKernelGGL(ln_kernel,     dim3(2048), dim3(256), 0, stream, x, lns, lnb, xx);
    hipLaunchKernelGGL(wtrans_kernel, dim3(1280), dim3(256), 0, stream, Wq, Wk, Wv, wqkt, wvt);
    hipLaunchKernelGGL(qk_gemm_kernel, dim3(128), dim3(256), 0, stream, xx, wqkt, qk);
    hipLaunchKernelGGL(v_gemm_kernel, dim3(512),  dim3(256), 0, stream, xe, wvt, v);
    hipLaunchKernelGGL(vtrans_kernel, dim3(1024), dim3(256), 0, stream, v, vt);
    hipLaunchKernelGGL(flash_kernel,  dim3(128 * nc), dim3(256), 0, stream, qk, vt, part, nc);
    hipLaunchKernelGGL(combine_kernel, dim3(4096), dim3(256), 0, stream, x, part, out, nc);
}

// Round 5
// 215.655 us; speedup vs baseline: 1.0310x; 1.0310x over previous
//
#include <hip/hip_runtime.h>

#define TT 8192
#define CC 512

typedef unsigned short u16;
typedef unsigned int u32;
typedef __attribute__((ext_vector_type(8))) short bf16x8;
typedef __attribute__((ext_vector_type(4))) short s16x4;
typedef __attribute__((ext_vector_type(4))) float f32x4;

__device__ __forceinline__ u16 f2bf(float f) {
    u32 u = __float_as_uint(f);
    return (u16)((u + 0x7FFFu + ((u >> 16) & 1u)) >> 16);
}

// ---------------- Kernel 1: LayerNorm -> xx (bf16)  +  x_emb -> xeb (bf16) ----------------
__global__ void ln_conv_kernel(const float* __restrict__ x,
                               const float* __restrict__ scale,
                               const float* __restrict__ bias,
                               const float* __restrict__ xe,
                               u16* __restrict__ xx,
                               u16* __restrict__ xeb) {
    int b = blockIdx.x;
    if (b < 2048) {
        int row = b * 4 + (threadIdx.x >> 6);
        int l = threadIdx.x & 63;
        const float4* xr = (const float4*)(x + (size_t)row * CC);
        float4 a = xr[l * 2], c = xr[l * 2 + 1];
        float s = a.x + a.y + a.z + a.w + c.x + c.y + c.z + c.w;
        float q = a.x*a.x + a.y*a.y + a.z*a.z + a.w*a.w
                + c.x*c.x + c.y*c.y + c.z*c.z + c.w*c.w;
        #pragma unroll
        for (int m = 1; m < 64; m <<= 1) {
            s += __shfl_xor(s, m, 64);
            q += __shfl_xor(q, m, 64);
        }
        float mu = s * (1.0f / CC);
        float var = q * (1.0f / CC) - mu * mu;
        float rs = rsqrtf(var + 1e-5f);
        const float4* sc4 = (const float4*)scale;
        const float4* bi4 = (const float4*)bias;
        float4 s1 = sc4[l * 2], s2 = sc4[l * 2 + 1];
        float4 b1 = bi4[l * 2], b2 = bi4[l * 2 + 1];
        bf16x8 o;
        o[0] = (short)f2bf((a.x - mu) * rs * s1.x + b1.x);
        o[1] = (short)f2bf((a.y - mu) * rs * s1.y + b1.y);
        o[2] = (short)f2bf((a.z - mu) * rs * s1.z + b1.z);
        o[3] = (short)f2bf((a.w - mu) * rs * s1.w + b1.w);
        o[4] = (short)f2bf((c.x - mu) * rs * s2.x + b2.x);
        o[5] = (short)f2bf((c.y - mu) * rs * s2.y + b2.y);
        o[6] = (short)f2bf((c.z - mu) * rs * s2.z + b2.z);
        o[7] = (short)f2bf((c.w - mu) * rs * s2.w + b2.w);
        *(bf16x8*)(xx + (size_t)row * CC + l * 8) = o;
    } else {
        size_t i = (size_t)(b - 2048) * 2048 + (size_t)threadIdx.x * 8;
        float4 a = *(const float4*)(xe + i);
        float4 c = *(const float4*)(xe + i + 4);
        bf16x8 o;
        o[0] = (short)f2bf(a.x); o[1] = (short)f2bf(a.y);
        o[2] = (short)f2bf(a.z); o[3] = (short)f2bf(a.w);
        o[4] = (short)f2bf(c.x); o[5] = (short)f2bf(c.y);
        o[6] = (short)f2bf(c.z); o[7] = (short)f2bf(c.w);
        *(bf16x8*)(xeb + i) = o;
    }
}

// ---------- Kernel 2: weight transposes -> WqkT [128][512], WvT [512][512] (bf16) ----------
__global__ void wtrans_kernel(const float* __restrict__ Wq,
                              const float* __restrict__ Wk,
                              const float* __restrict__ Wv,
                              u16* __restrict__ wqkt,
                              u16* __restrict__ wvt) {
    int tid = blockIdx.x * 256 + threadIdx.x;   // 0 .. 327679
    if (tid < 65536) {
        int c = tid >> 9, k = tid & 511;
        float w = (c < 64) ? Wq[k * 64 + c] : Wk[k * 64 + (c - 64)];
        wqkt[tid] = f2bf(w);
    } else {
        int i = tid - 65536;
        int c = i >> 9, k = i & 511;
        wvt[i] = f2bf(Wv[k * 512 + c]);
    }
}

// ---------- Kernel 3: qk = xx @ [Wq|Wk], q scaled by 1/8 -> qk bf16 [T][128] ----------
__global__ __launch_bounds__(128) void qk_gemm_kernel(const u16* __restrict__ xx,
                                                      const u16* __restrict__ wqkt,
                                                      u16* __restrict__ qk) {
    int w = threadIdx.x >> 6;          // 0..1
    int l = threadIdx.x & 63;
    int l15 = l & 15, g = l >> 4;
    int r0 = blockIdx.x * 32 + w * 16;

    f32x4 acc[8];
    #pragma unroll
    for (int i = 0; i < 8; ++i) acc[i] = (f32x4){0.f, 0.f, 0.f, 0.f};

    for (int kk = 0; kk < 16; ++kk) {
        int k = kk * 32 + g * 8;
        bf16x8 af = *(const bf16x8*)(xx + (size_t)(r0 + l15) * CC + k);
        #pragma unroll
        for (int Nt = 0; Nt < 8; ++Nt) {
            int c = Nt * 16 + l15;
            bf16x8 bfr = *(const bf16x8*)(wqkt + c * CC + k);
            acc[Nt] = __builtin_amdgcn_mfma_f32_16x16x32_bf16(af, bfr, acc[Nt], 0, 0, 0);
        }
    }
    #pragma unroll
    for (int Nt = 0; Nt < 8; ++Nt) {
        int c = Nt * 16 + l15;
        float scl = (c < 64) ? 0.125f : 1.0f;
        #pragma unroll
        for (int jj = 0; jj < 4; ++jj) {
            int rg = r0 + g * 4 + jj;
            qk[rg * 128 + c] = f2bf(acc[Nt][jj] * scl);
        }
    }
}

// ---------- Kernel 4: vT = (x_emb @ Wv)^T -> vt bf16 [512][T]  (direct transposed store) ----------
__global__ __launch_bounds__(256) void v_gemm_kernel(const u16* __restrict__ xeb,
                                                     const u16* __restrict__ wvt,
                                                     u16* __restrict__ vt) {
    int w = threadIdx.x >> 6;
    int l = threadIdx.x & 63;
    int l15 = l & 15, g = l >> 4;
    int bm = blockIdx.x >> 2, bn = blockIdx.x & 3;
    int r0 = bm * 64 + w * 16;
    int c0 = bn * 128;

    f32x4 acc[8];
    #pragma unroll
    for (int i = 0; i < 8; ++i) acc[i] = (f32x4){0.f, 0.f, 0.f, 0.f};

    for (int kk = 0; kk < 16; ++kk) {
        int k = kk * 32 + g * 8;
        bf16x8 af = *(const bf16x8*)(xeb + (size_t)(r0 + l15) * CC + k);
        #pragma unroll
        for (int Nt = 0; Nt < 8; ++Nt) {
            int c = c0 + Nt * 16 + l15;
            bf16x8 bfr = *(const bf16x8*)(wvt + c * CC + k);
            acc[Nt] = __builtin_amdgcn_mfma_f32_16x16x32_bf16(af, bfr, acc[Nt], 0, 0, 0);
        }
    }
    #pragma unroll
    for (int Nt = 0; Nt < 8; ++Nt) {
        int c = c0 + Nt * 16 + l15;
        s16x4 o4;
        o4[0] = (short)f2bf(acc[Nt][0]);
        o4[1] = (short)f2bf(acc[Nt][1]);
        o4[2] = (short)f2bf(acc[Nt][2]);
        o4[3] = (short)f2bf(acc[Nt][3]);
        *(s16x4*)(vt + (size_t)c * TT + r0 + g * 4) = o4;
    }
}

// ---------- Kernel 5: flash (causal QK^T -> mask -> PV), BM=128, 8 waves, adaptive chunks ----------
__global__ __launch_bounds__(512, 2) void flash_kernel(const u16* __restrict__ qk,
                                                       const u16* __restrict__ vt,
                                                       float* __restrict__ part,
                                                       int CT) {
    __shared__ u16 Klds[64 * 64];    // [s][a] XOR-swizzled 16B slots
    __shared__ u16 Slds[128 * 64];   // [r][s] XOR-swizzled 16B slots

    const int tid = threadIdx.x;
    const int w = tid >> 6;
    const int l = tid & 63;
    const int l15 = l & 15;
    const int g = l >> 4;
    const int wr = w >> 2;           // 0..1 : row half
    const int wc = w & 3;            // 0..3 : col quarter

    // decode blockIdx -> (rt, ch); big-rt-first dispatch order
    const int total = (int)gridDim.x;
    int b2 = total - 1 - (int)blockIdx.x;
    int rt = 0, base = 0;
    for (;;) {
        int nt = 2 * rt + 2;
        int nc = (nt + CT - 1) / CT;
        if (b2 < base + nc) break;
        base += nc; ++rt;
    }
    const int nt = 2 * rt + 2;
    const int nc = (nt + CT - 1) / CT;
    const int ch = b2 - base;
    const int t_lo = ch * nt / nc;
    const int t_hi = (ch + 1) * nt / nc;
    const int slot = b2;

    // Q fragments for this wave's S-slice rows (16 rows), pre-scaled by 1/8
    const int qrow = rt * 128 + wr * 64 + wc * 16 + l15;
    const bf16x8 qs0 = *(const bf16x8*)(qk + qrow * 128 + g * 8);
    const bf16x8 qs1 = *(const bf16x8*)(qk + qrow * 128 + 32 + g * 8);

    f32x4 acc[4][8];                 // O[wr*64 + Mt*16 rows][wc*128 + Nt*16 cols]
    #pragma unroll
    for (int m = 0; m < 4; ++m)
        #pragma unroll
        for (int n = 0; n < 8; ++n) acc[m][n] = (f32x4){0.f, 0.f, 0.f, 0.f};

    const int sI = tid >> 3, p = tid & 7;
    const int a8 = (p ^ (sI & 7)) << 3;      // pre-swizzled source for linear-ish LDS slot

    // prologue: stage K(t_lo)
    {
        bf16x8 k0 = *(const bf16x8*)(qk + (size_t)(t_lo * 64 + sI) * 128 + 64 + a8);
        *(bf16x8*)&Klds[sI * 64 + p * 8] = k0;
    }
    __syncthreads();

    for (int j = t_lo; j < t_hi; ++j) {
        const int s0 = j * 64;

        bf16x8 knext;
        if (j + 1 < t_hi)
            knext = *(const bf16x8*)(qk + (size_t)((j + 1) * 64 + sI) * 128 + 64 + a8);

        // QK^T : this wave computes S rows [wr*64+wc*16, +16), all 64 s
        f32x4 sacc[4];
        #pragma unroll
        for (int Nt = 0; Nt < 4; ++Nt) sacc[Nt] = (f32x4){0.f, 0.f, 0.f, 0.f};
        #pragma unroll
        for (int Nt = 0; Nt < 4; ++Nt) {
            int srow = Nt * 16 + l15;
            #pragma unroll
            for (int ka = 0; ka < 2; ++ka) {
                int sl = (ka * 4 + g) ^ (srow & 7);
                bf16x8 kf = *(const bf16x8*)&Klds[srow * 64 + sl * 8];
                sacc[Nt] = __builtin_amdgcn_mfma_f32_16x16x32_bf16(
                    (ka == 0) ? qs0 : qs1, kf, sacc[Nt], 0, 0, 0);
            }
        }

        // causal mask on the two diagonal tiles + convert + write S (swizzled)
        const bool diag = (j >= 2 * rt);
        #pragma unroll
        for (int Nt = 0; Nt < 4; ++Nt) {
            int scol = Nt * 16 + l15;
            int sg = s0 + scol;
            #pragma unroll
            for (int jj = 0; jj < 4; ++jj) {
                int row = wr * 64 + wc * 16 + g * 4 + jj;
                float val = sacc[Nt][jj];
                if (diag && sg > rt * 128 + row) val = 0.f;
                Slds[row * 64 + ((((scol >> 3) ^ (row & 7)) << 3) + (scol & 7))] = f2bf(val);
            }
        }
        __syncthreads();                 // S visible; K reads done

        if (j + 1 < t_hi)
            *(bf16x8*)&Klds[sI * 64 + p * 8] = knext;   // hidden under PV

        // PV : A = S rows [wr*64, +64), B = vt cols [wc*128, +128)
        bf16x8 sf[4][2];
        #pragma unroll
        for (int Mt = 0; Mt < 4; ++Mt) {
            int row = wr * 64 + Mt * 16 + l15;
            #pragma unroll
            for (int ka = 0; ka < 2; ++ka) {
                int sl = (ka * 4 + g) ^ (row & 7);
                sf[Mt][ka] = *(const bf16x8*)&Slds[row * 64 + sl * 8];
            }
        }
        #pragma unroll
        for (int Nt = 0; Nt < 8; ++Nt) {
            int cv = wc * 128 + Nt * 16 + l15;
            #pragma unroll
            for (int ka = 0; ka < 2; ++ka) {
                bf16x8 vf = *(const bf16x8*)(vt + (size_t)cv * TT + s0 + ka * 32 + g * 8);
                #pragma unroll
                for (int Mt = 0; Mt < 4; ++Mt)
                    acc[Mt][Nt] = __builtin_amdgcn_mfma_f32_16x16x32_bf16(
                        sf[Mt][ka], vf, acc[Mt][Nt], 0, 0, 0);
            }
        }
        __syncthreads();                 // S reads done; K(j+1) visible
    }

    // write partial O tile [128][512] f32
    float* pb = part + (size_t)slot * (128 * 512);
    #pragma unroll
    for (int Mt = 0; Mt < 4; ++Mt) {
        #pragma unroll
        for (int Nt = 0; Nt < 8; ++Nt) {
            int col = wc * 128 + Nt * 16 + l15;
            #pragma unroll
            for (int jj = 0; jj < 4; ++jj) {
                int row = wr * 64 + Mt * 16 + g * 4 + jj;
                pb[row * 512 + col] = acc[Mt][Nt][jj];
            }
        }
    }
}

// ---------- Kernel 6: out = x + sum(partial chunks of this row-tile) ----------
__global__ void combine_kernel(const float* __restrict__ x,
                               const float* __restrict__ part,
                               float* __restrict__ out, int CT) {
    int i = blockIdx.x * 256 + threadIdx.x;   // float4 index, 1048576 total
    int row = i >> 7;
    int rt = row >> 7;
    int base = 0;
    for (int r = 0; r < rt; ++r) base += (2 * r + 2 + CT - 1) / CT;
    int nc = (2 * rt + 2 + CT - 1) / CT;
    float4 v = ((const float4*)x)[i];
    int rloc = row & 127;
    int c4 = i & 127;
    for (int s = 0; s < nc; ++s) {
        const float4* p4 = (const float4*)(part + (size_t)(base + s) * (128 * 512));
        float4 p = p4[rloc * 128 + c4];
        v.x += p.x; v.y += p.y; v.z += p.z; v.w += p.w;
    }
    ((float4*)out)[i] = v;
}

extern "C" void kernel_launch(void* const* d_in, const int* in_sizes, int n_in,
                              void* d_out, int out_size, void* d_ws, size_t ws_size,
                              hipStream_t stream) {
    (void)in_sizes; (void)n_in; (void)out_size;
    const float* x    = (const float*)d_in[0];
    const float* xe   = (const float*)d_in[1];
    const float* lns  = (const float*)d_in[2];
    const float* lnb  = (const float*)d_in[3];
    const float* Wq   = (const float*)d_in[4];
    const float* Wk   = (const float*)d_in[5];
    const float* Wv   = (const float*)d_in[6];
    float* out = (float*)d_out;
    char* ws = (char*)d_ws;

    size_t off_xx   = 0;                                   // bf16 [8192][512]  8 MB
    size_t off_qk   = off_xx   + (size_t)TT * CC * 2;      // bf16 [8192][128]  2 MB
    size_t off_wqkt = off_qk   + (size_t)TT * 128 * 2;     // bf16 [128][512]
    size_t off_wvt  = off_wqkt + (size_t)128 * 512 * 2;    // bf16 [512][512]
    size_t off_xeb  = off_wvt  + (size_t)512 * 512 * 2;    // bf16 [8192][512]  8 MB
    size_t off_vt   = off_xeb  + (size_t)TT * CC * 2;      // bf16 [512][8192]  8 MB
    size_t off_part = off_vt   + (size_t)TT * CC * 2;      // f32 slots x 256 KB

    // pick chunk size CT (in 64-wide s-tiles) so partials fit in ws
    int CT = 8, slots = 0;
    for (;;) {
        slots = 0;
        for (int rt = 0; rt < 64; ++rt) slots += (2 * rt + 2 + CT - 1) / CT;
        if (off_part + (size_t)slots * (128 * 512) * 4 <= ws_size || CT >= 128) break;
        CT *= 2;
    }

    u16* xx   = (u16*)(ws + off_xx);
    u16* qk   = (u16*)(ws + off_qk);
    u16* wqkt = (u16*)(ws + off_wqkt);
    u16* wvt  = (u16*)(ws + off_wvt);
    u16* xeb  = (u16*)(ws + off_xeb);
    u16* vt   = (u16*)(ws + off_vt);
    float* part = (float*)(ws + off_part);

    hipLaunchKernelGGL(ln_conv_kernel, dim3(4096), dim3(256), 0, stream, x, lns, lnb, xe, xx, xeb);
    hipLaunchKernelGGL(wtrans_kernel,  dim3(1280), dim3(256), 0, stream, Wq, Wk, Wv, wqkt, wvt);
    hipLaunchKernelGGL(qk_gemm_kernel, dim3(256),  dim3(128), 0, stream, xx, wqkt, qk);
    hipLaunchKernelGGL(v_gemm_kernel,  dim3(512),  dim3(256), 0, stream, xeb, wvt, vt);
    hipLaunchKernelGGL(flash_kernel,   dim3(slots), dim3(512), 0, stream, qk, vt, part, CT);
    hipLaunchKernelGGL(combine_kernel, dim3(4096), dim3(256), 0, stream, x, part, out, CT);
}

// Round 6
// 172.503 us; speedup vs baseline: 1.2889x; 1.2502x over previous
//
#include <hip/hip_runtime.h>

#define TT 8192
#define CC 512

typedef unsigned short u16;
typedef unsigned int u32;
typedef __attribute__((ext_vector_type(8))) short bf16x8;
typedef __attribute__((ext_vector_type(4))) short s16x4;
typedef __attribute__((ext_vector_type(4))) float f32x4;

#define VMCNT(N) asm volatile("s_waitcnt vmcnt(" #N ")" ::: "memory")
#define LGKM0()  asm volatile("s_waitcnt lgkmcnt(0)" ::: "memory")

__device__ __forceinline__ u16 f2bf(float f) {
    u32 u = __float_as_uint(f);
    return (u16)((u + 0x7FFFu + ((u >> 16) & 1u)) >> 16);
}

__device__ __forceinline__ void gld16(const u16* g, u16* l) {
    __builtin_amdgcn_global_load_lds(
        (const __attribute__((address_space(1))) u32*)g,
        (__attribute__((address_space(3))) u32*)l, 16, 0, 0);
}

// ---------------- Kernel 1: LayerNorm -> xx (bf16) ----------------
__global__ void ln_kernel(const float* __restrict__ x,
                          const float* __restrict__ scale,
                          const float* __restrict__ bias,
                          u16* __restrict__ xx) {
    int row = blockIdx.x * 4 + (threadIdx.x >> 6);
    int l = threadIdx.x & 63;
    const float4* xr = (const float4*)(x + (size_t)row * CC);
    float4 a = xr[l * 2], b = xr[l * 2 + 1];
    float s = a.x + a.y + a.z + a.w + b.x + b.y + b.z + b.w;
    float q = a.x*a.x + a.y*a.y + a.z*a.z + a.w*a.w
            + b.x*b.x + b.y*b.y + b.z*b.z + b.w*b.w;
    #pragma unroll
    for (int m = 1; m < 64; m <<= 1) {
        s += __shfl_xor(s, m, 64);
        q += __shfl_xor(q, m, 64);
    }
    float mu = s * (1.0f / CC);
    float var = q * (1.0f / CC) - mu * mu;
    float rs = rsqrtf(var + 1e-5f);
    const float4* sc4 = (const float4*)scale;
    const float4* bi4 = (const float4*)bias;
    float4 s1 = sc4[l * 2], s2 = sc4[l * 2 + 1];
    float4 b1 = bi4[l * 2], b2 = bi4[l * 2 + 1];
    bf16x8 o;
    o[0] = (short)f2bf((a.x - mu) * rs * s1.x + b1.x);
    o[1] = (short)f2bf((a.y - mu) * rs * s1.y + b1.y);
    o[2] = (short)f2bf((a.z - mu) * rs * s1.z + b1.z);
    o[3] = (short)f2bf((a.w - mu) * rs * s1.w + b1.w);
    o[4] = (short)f2bf((b.x - mu) * rs * s2.x + b2.x);
    o[5] = (short)f2bf((b.y - mu) * rs * s2.y + b2.y);
    o[6] = (short)f2bf((b.z - mu) * rs * s2.z + b2.z);
    o[7] = (short)f2bf((b.w - mu) * rs * s2.w + b2.w);
    *(bf16x8*)(xx + (size_t)row * CC + l * 8) = o;
}

// ---------- Kernel 2: weight transposes -> WqkT [128][512], WvT [512][512] (bf16) ----------
__global__ void wtrans_kernel(const float* __restrict__ Wq,
                              const float* __restrict__ Wk,
                              const float* __restrict__ Wv,
                              u16* __restrict__ wqkt,
                              u16* __restrict__ wvt) {
    int tid = blockIdx.x * 256 + threadIdx.x;   // 0 .. 327679
    if (tid < 65536) {
        int c = tid >> 9, k = tid & 511;
        float w = (c < 64) ? Wq[k * 64 + c] : Wk[k * 64 + (c - 64)];
        wqkt[tid] = f2bf(w);
    } else {
        int i = tid - 65536;
        int c = i >> 9, k = i & 511;
        wvt[i] = f2bf(Wv[k * 512 + c]);
    }
}

// ---------- Kernel 3: qk = xx @ [Wq|Wk], q scaled by 1/8 -> qk bf16 [T][128] ----------
__global__ __launch_bounds__(128) void qk_gemm_kernel(const u16* __restrict__ xx,
                                                      const u16* __restrict__ wqkt,
                                                      u16* __restrict__ qk) {
    int w = threadIdx.x >> 6;          // 0..1
    int l = threadIdx.x & 63;
    int l15 = l & 15, g = l >> 4;
    int r0 = blockIdx.x * 32 + w * 16;

    f32x4 acc[8];
    #pragma unroll
    for (int i = 0; i < 8; ++i) acc[i] = (f32x4){0.f, 0.f, 0.f, 0.f};

    for (int kk = 0; kk < 16; ++kk) {
        int k = kk * 32 + g * 8;
        bf16x8 af = *(const bf16x8*)(xx + (size_t)(r0 + l15) * CC + k);
        #pragma unroll
        for (int Nt = 0; Nt < 8; ++Nt) {
            int c = Nt * 16 + l15;
            bf16x8 bfr = *(const bf16x8*)(wqkt + c * CC + k);
            acc[Nt] = __builtin_amdgcn_mfma_f32_16x16x32_bf16(af, bfr, acc[Nt], 0, 0, 0);
        }
    }
    #pragma unroll
    for (int Nt = 0; Nt < 8; ++Nt) {
        int c = Nt * 16 + l15;
        float scl = (c < 64) ? 0.125f : 1.0f;
        #pragma unroll
        for (int jj = 0; jj < 4; ++jj) {
            int rg = r0 + g * 4 + jj;
            qk[rg * 128 + c] = f2bf(acc[Nt][jj] * scl);
        }
    }
}

// ---------- Kernel 4: vT = (x_emb @ Wv)^T -> vt bf16 [512][T]  (f32 input, transposed store) ----------
__global__ __launch_bounds__(256) void v_gemm_kernel(const float* __restrict__ xe,
                                                     const u16* __restrict__ wvt,
                                                     u16* __restrict__ vt) {
    int w = threadIdx.x >> 6;
    int l = threadIdx.x & 63;
    int l15 = l & 15, g = l >> 4;
    int bm = blockIdx.x >> 2, bn = blockIdx.x & 3;
    int r0 = bm * 64 + w * 16;
    int c0 = bn * 128;

    f32x4 acc[8];
    #pragma unroll
    for (int i = 0; i < 8; ++i) acc[i] = (f32x4){0.f, 0.f, 0.f, 0.f};

    for (int kk = 0; kk < 16; ++kk) {
        int k = kk * 32 + g * 8;
        const float4* ap = (const float4*)(xe + (size_t)(r0 + l15) * CC + k);
        float4 a1 = ap[0], a2 = ap[1];
        bf16x8 af;
        af[0] = (short)f2bf(a1.x); af[1] = (short)f2bf(a1.y);
        af[2] = (short)f2bf(a1.z); af[3] = (short)f2bf(a1.w);
        af[4] = (short)f2bf(a2.x); af[5] = (short)f2bf(a2.y);
        af[6] = (short)f2bf(a2.z); af[7] = (short)f2bf(a2.w);
        #pragma unroll
        for (int Nt = 0; Nt < 8; ++Nt) {
            int c = c0 + Nt * 16 + l15;
            bf16x8 bfr = *(const bf16x8*)(wvt + c * CC + k);
            acc[Nt] = __builtin_amdgcn_mfma_f32_16x16x32_bf16(af, bfr, acc[Nt], 0, 0, 0);
        }
    }
    #pragma unroll
    for (int Nt = 0; Nt < 8; ++Nt) {
        int c = c0 + Nt * 16 + l15;
        s16x4 o4;
        o4[0] = (short)f2bf(acc[Nt][0]);
        o4[1] = (short)f2bf(acc[Nt][1]);
        o4[2] = (short)f2bf(acc[Nt][2]);
        o4[3] = (short)f2bf(acc[Nt][3]);
        *(s16x4*)(vt + (size_t)c * TT + r0 + g * 4) = o4;
    }
}

// ---------- Kernel 5: flash, BM=128, 8 waves, async V->LDS dbuf + counted vmcnt ----------
__global__ __launch_bounds__(512, 2) void flash_kernel(const u16* __restrict__ qk,
                                                       const u16* __restrict__ vt,
                                                       float* __restrict__ part,
                                                       int CT) {
    extern __shared__ u16 smem[];
    u16* const Klds = smem;             // [64 s][64 a] XOR-swizzled, 8KB
    u16* const Slds = smem + 4096;      // [128 r][64 s] XOR-swizzled, 16KB
    u16* const Vbuf = smem + 12288;     // 2 x [512 c][64 s] XOR-swizzled, 2x64KB

    const int tid = threadIdx.x;
    const int w = tid >> 6;
    const int l = tid & 63;
    const int l15 = l & 15;
    const int g = l >> 4;
    const int wr = w >> 2;              // 0..1 row half
    const int wc = w & 3;               // 0..3 col quarter

    // decode blockIdx -> (rt, ch); big-rt-first dispatch order
    const int total = (int)gridDim.x;
    int b2 = total - 1 - (int)blockIdx.x;
    int rt = 0, base = 0;
    for (;;) {
        int nt_ = 2 * rt + 2;
        int nc_ = (nt_ + CT - 1) / CT;
        if (b2 < base + nc_) break;
        base += nc_; ++rt;
    }
    const int nt = 2 * rt + 2;
    const int nc = (nt + CT - 1) / CT;
    const int ch = b2 - base;
    const int t_lo = ch * nt / nc;
    const int t_hi = (ch + 1) * nt / nc;
    const int slot = b2;

    // Q fragments (16 rows per wave), already scaled by 1/8
    const int qrow = rt * 128 + wr * 64 + wc * 16 + l15;
    const bf16x8 qs0 = *(const bf16x8*)(qk + qrow * 128 + g * 8);
    const bf16x8 qs1 = *(const bf16x8*)(qk + qrow * 128 + 32 + g * 8);

    f32x4 acc[4][8];
    #pragma unroll
    for (int m = 0; m < 4; ++m)
        #pragma unroll
        for (int n = 0; n < 8; ++n) acc[m][n] = (f32x4){0.f, 0.f, 0.f, 0.f};

    // K staging indices (reg->LDS, swizzled)
    const int sI = tid >> 3, p = tid & 7;
    const int a8 = (p ^ (sI & 7)) << 3;
    // V staging indices (global_load_lds, pre-swizzled source, linear LDS)
    const int vsub = l >> 3, vp = l & 7;

    // prologue: stage V(t_lo) -> buf0 (async), K(t_lo) reg->LDS
    {
        #pragma unroll
        for (int i = 0; i < 8; ++i) {
            int c = i * 64 + w * 8 + vsub;
            gld16(vt + (size_t)c * TT + t_lo * 64 + ((vp ^ (c & 7)) << 3),
                  Vbuf + (i * 8 + w) * 512 + l * 8);
        }
        bf16x8 k0 = *(const bf16x8*)(qk + (size_t)(t_lo * 64 + sI) * 128 + 64 + a8);
        *(bf16x8*)&Klds[sI * 64 + p * 8] = k0;
    }
    __syncthreads();   // full drain once (prologue only)

    int cur = 0;
    for (int j = t_lo; j < t_hi; ++j) {
        const int s0 = j * 64;
        const bool more = (j + 1 < t_hi);

        bf16x8 knext;
        if (more) {
            // A: async-stage V(j+1) into other buffer (8 vm ops)
            u16* vdst = Vbuf + (cur ^ 1) * 32768;
            #pragma unroll
            for (int i = 0; i < 8; ++i) {
                int c = i * 64 + w * 8 + vsub;
                gld16(vt + (size_t)c * TT + s0 + 64 + ((vp ^ (c & 7)) << 3),
                      vdst + (i * 8 + w) * 512 + l * 8);
            }
            // B: K(j+1) -> reg (1 vm op)
            knext = *(const bf16x8*)(qk + (size_t)((j + 1) * 64 + sI) * 128 + 64 + a8);
        }

        // C: QK^T (8 MFMA/wave)
        f32x4 sacc[4];
        #pragma unroll
        for (int Nt = 0; Nt < 4; ++Nt) sacc[Nt] = (f32x4){0.f, 0.f, 0.f, 0.f};
        #pragma unroll
        for (int Nt = 0; Nt < 4; ++Nt) {
            int srow = Nt * 16 + l15;
            #pragma unroll
            for (int ka = 0; ka < 2; ++ka) {
                int sl = (ka * 4 + g) ^ (srow & 7);
                bf16x8 kf = *(const bf16x8*)&Klds[srow * 64 + sl * 8];
                sacc[Nt] = __builtin_amdgcn_mfma_f32_16x16x32_bf16(
                    (ka == 0) ? qs0 : qs1, kf, sacc[Nt], 0, 0, 0);
            }
        }

        // D: causal mask + cvt + S->LDS (swizzled)
        const bool diag = (j >= 2 * rt);
        #pragma unroll
        for (int Nt = 0; Nt < 4; ++Nt) {
            int scol = Nt * 16 + l15;
            int sg = s0 + scol;
            #pragma unroll
            for (int jj = 0; jj < 4; ++jj) {
                int row = wr * 64 + wc * 16 + g * 4 + jj;
                float val = sacc[Nt][jj];
                if (diag && sg > rt * 128 + row) val = 0.f;
                Slds[row * 64 + ((((scol >> 3) ^ (row & 7)) << 3) + (scol & 7))] = f2bf(val);
            }
        }

        // E: V(j) DMA (issued last iter) complete; keep this iter's 9 ops in flight
        if (more) { VMCNT(9); } else { VMCNT(0); }
        LGKM0();                              // S writes + K reads drained
        __builtin_amdgcn_s_barrier();         // F

        // G: K(j+1) reg -> LDS (hidden under PV)
        if (more) *(bf16x8*)&Klds[sI * 64 + p * 8] = knext;

        // H: PV — A = S rows [wr*64,+64) from LDS, B = V cols [wc*128,+128) from LDS
        const u16* Vl = Vbuf + cur * 32768;
        bf16x8 sf[4][2];
        #pragma unroll
        for (int Mt = 0; Mt < 4; ++Mt) {
            int row = wr * 64 + Mt * 16 + l15;
            #pragma unroll
            for (int ka = 0; ka < 2; ++ka) {
                int sl = (ka * 4 + g) ^ (row & 7);
                sf[Mt][ka] = *(const bf16x8*)&Slds[row * 64 + sl * 8];
            }
        }
        #pragma unroll
        for (int Nt = 0; Nt < 8; ++Nt) {
            int cv = wc * 128 + Nt * 16 + l15;
            #pragma unroll
            for (int ka = 0; ka < 2; ++ka) {
                int phys = (ka * 4 + g) ^ (cv & 7);
                bf16x8 vf = *(const bf16x8*)&Vl[cv * 64 + phys * 8];
                #pragma unroll
                for (int Mt = 0; Mt < 4; ++Mt)
                    acc[Mt][Nt] = __builtin_amdgcn_mfma_f32_16x16x32_bf16(
                        sf[Mt][ka], vf, acc[Mt][Nt], 0, 0, 0);
            }
        }

        LGKM0();                              // S/V/K ds ops drained
        __builtin_amdgcn_s_barrier();         // I
        cur ^= 1;
    }

    // write partial O tile [128][512] f32
    float* pb = part + (size_t)slot * (128 * 512);
    #pragma unroll
    for (int Mt = 0; Mt < 4; ++Mt) {
        #pragma unroll
        for (int Nt = 0; Nt < 8; ++Nt) {
            int col = wc * 128 + Nt * 16 + l15;
            #pragma unroll
            for (int jj = 0; jj < 4; ++jj) {
                int row = wr * 64 + Mt * 16 + g * 4 + jj;
                pb[row * 512 + col] = acc[Mt][Nt][jj];
            }
        }
    }
}

// ---------- Kernel 6: out = x + sum(partial chunks of this row-tile) ----------
__global__ void combine_kernel(const float* __restrict__ x,
                               const float* __restrict__ part,
                               float* __restrict__ out, int CT) {
    int i = blockIdx.x * 256 + threadIdx.x;   // float4 index, 1048576 total
    int row = i >> 7;
    int rt = row >> 7;
    int base = 0;
    for (int r = 0; r < rt; ++r) base += (2 * r + 2 + CT - 1) / CT;
    int nc = (2 * rt + 2 + CT - 1) / CT;
    float4 v = ((const float4*)x)[i];
    int rloc = row & 127;
    int c4 = i & 127;
    for (int s = 0; s < nc; ++s) {
        const float4* p4 = (const float4*)(part + (size_t)(base + s) * (128 * 512));
        float4 p = p4[rloc * 128 + c4];
        v.x += p.x; v.y += p.y; v.z += p.z; v.w += p.w;
    }
    ((float4*)out)[i] = v;
}

extern "C" void kernel_launch(void* const* d_in, const int* in_sizes, int n_in,
                              void* d_out, int out_size, void* d_ws, size_t ws_size,
                              hipStream_t stream) {
    (void)in_sizes; (void)n_in; (void)out_size;
    const float* x    = (const float*)d_in[0];
    const float* xe   = (const float*)d_in[1];
    const float* lns  = (const float*)d_in[2];
    const float* lnb  = (const float*)d_in[3];
    const float* Wq   = (const float*)d_in[4];
    const float* Wk   = (const float*)d_in[5];
    const float* Wv   = (const float*)d_in[6];
    float* out = (float*)d_out;
    char* ws = (char*)d_ws;

    size_t off_xx   = 0;                                   // bf16 [8192][512]  8 MB
    size_t off_qk   = off_xx   + (size_t)TT * CC * 2;      // bf16 [8192][128]  2 MB
    size_t off_wqkt = off_qk   + (size_t)TT * 128 * 2;     // bf16 [128][512]
    size_t off_wvt  = off_wqkt + (size_t)128 * 512 * 2;    // bf16 [512][512]
    size_t off_vt   = off_wvt  + (size_t)512 * 512 * 2;    // bf16 [512][8192]  8 MB
    size_t off_part = off_vt   + (size_t)TT * CC * 2;      // f32 slots x 256 KB

    // pick chunk size CT (in 64-wide s-tiles) so partials fit in ws
    int CT = 16, slots = 0;
    for (;;) {
        slots = 0;
        for (int rt = 0; rt < 64; ++rt) slots += (2 * rt + 2 + CT - 1) / CT;
        if (off_part + (size_t)slots * (128 * 512) * 4 <= ws_size || CT >= 128) break;
        CT *= 2;
    }

    u16* xx   = (u16*)(ws + off_xx);
    u16* qk   = (u16*)(ws + off_qk);
    u16* wqkt = (u16*)(ws + off_wqkt);
    u16* wvt  = (u16*)(ws + off_wvt);
    u16* vt   = (u16*)(ws + off_vt);
    float* part = (float*)(ws + off_part);

    const size_t flash_lds = (size_t)(4096 + 8192 + 2 * 32768) * sizeof(u16);  // 152 KB

    hipLaunchKernelGGL(ln_kernel,      dim3(2048), dim3(256), 0, stream, x, lns, lnb, xx);
    hipLaunchKernelGGL(wtrans_kernel,  dim3(1280), dim3(256), 0, stream, Wq, Wk, Wv, wqkt, wvt);
    hipLaunchKernelGGL(qk_gemm_kernel, dim3(256),  dim3(128), 0, stream, xx, wqkt, qk);
    hipLaunchKernelGGL(v_gemm_kernel,  dim3(512),  dim3(256), 0, stream, xe, wvt, vt);
    hipLaunchKernelGGL(flash_kernel,   dim3(slots), dim3(512), flash_lds, stream, qk, vt, part, CT);
    hipLaunchKernelGGL(combine_kernel, dim3(4096), dim3(256), 0, stream, x, part, out, CT);
}

// Round 7
// 159.504 us; speedup vs baseline: 1.3939x; 1.0815x over previous
//
#include <hip/hip_runtime.h>

#define TT 8192
#define CC 512

typedef unsigned short u16;
typedef unsigned int u32;
typedef __attribute__((ext_vector_type(8))) short bf16x8;
typedef __attribute__((ext_vector_type(4))) short s16x4;
typedef __attribute__((ext_vector_type(4))) float f32x4;

#define VMCNT(N) asm volatile("s_waitcnt vmcnt(" #N ")" ::: "memory")
#define LGKM0()  asm volatile("s_waitcnt lgkmcnt(0)" ::: "memory")

__device__ __forceinline__ u16 f2bf(float f) {
    u32 u = __float_as_uint(f);
    return (u16)((u + 0x7FFFu + ((u >> 16) & 1u)) >> 16);
}

__device__ __forceinline__ void gld16(const u16* g, u16* l) {
    __builtin_amdgcn_global_load_lds(
        (const __attribute__((address_space(1))) u32*)g,
        (__attribute__((address_space(3))) u32*)l, 16, 0, 0);
}

// ---------------- Kernel 1: LayerNorm -> xx (bf16)  +  weight transposes ----------------
__global__ void lnw_kernel(const float* __restrict__ x,
                           const float* __restrict__ scale,
                           const float* __restrict__ bias,
                           const float* __restrict__ Wq,
                           const float* __restrict__ Wk,
                           const float* __restrict__ Wv,
                           u16* __restrict__ xx,
                           u16* __restrict__ wqkt,
                           u16* __restrict__ wvt) {
    int b = blockIdx.x;
    if (b < 2048) {
        int row = b * 4 + (threadIdx.x >> 6);
        int l = threadIdx.x & 63;
        const float4* xr = (const float4*)(x + (size_t)row * CC);
        float4 a = xr[l * 2], c = xr[l * 2 + 1];
        float s = a.x + a.y + a.z + a.w + c.x + c.y + c.z + c.w;
        float q = a.x*a.x + a.y*a.y + a.z*a.z + a.w*a.w
                + c.x*c.x + c.y*c.y + c.z*c.z + c.w*c.w;
        #pragma unroll
        for (int m = 1; m < 64; m <<= 1) {
            s += __shfl_xor(s, m, 64);
            q += __shfl_xor(q, m, 64);
        }
        float mu = s * (1.0f / CC);
        float var = q * (1.0f / CC) - mu * mu;
        float rs = rsqrtf(var + 1e-5f);
        const float4* sc4 = (const float4*)scale;
        const float4* bi4 = (const float4*)bias;
        float4 s1 = sc4[l * 2], s2 = sc4[l * 2 + 1];
        float4 b1 = bi4[l * 2], b2 = bi4[l * 2 + 1];
        bf16x8 o;
        o[0] = (short)f2bf((a.x - mu) * rs * s1.x + b1.x);
        o[1] = (short)f2bf((a.y - mu) * rs * s1.y + b1.y);
        o[2] = (short)f2bf((a.z - mu) * rs * s1.z + b1.z);
        o[3] = (short)f2bf((a.w - mu) * rs * s1.w + b1.w);
        o[4] = (short)f2bf((c.x - mu) * rs * s2.x + b2.x);
        o[5] = (short)f2bf((c.y - mu) * rs * s2.y + b2.y);
        o[6] = (short)f2bf((c.z - mu) * rs * s2.z + b2.z);
        o[7] = (short)f2bf((c.w - mu) * rs * s2.w + b2.w);
        *(bf16x8*)(xx + (size_t)row * CC + l * 8) = o;
    } else {
        int tid = (b - 2048) * 256 + threadIdx.x;   // 0 .. 327679
        if (tid < 65536) {
            int c = tid >> 9, k = tid & 511;
            float w = (c < 64) ? Wq[k * 64 + c] : Wk[k * 64 + (c - 64)];
            wqkt[tid] = f2bf(w);
        } else {
            int i = tid - 65536;
            int c = i >> 9, k = i & 511;
            wvt[i] = f2bf(Wv[k * 512 + c]);
        }
    }
}

// ---------- Kernel 2: qk = xx @ [Wq|Wk], q scaled by 1/8 -> qk bf16 [T][128] ----------
__global__ __launch_bounds__(128) void qk_gemm_kernel(const u16* __restrict__ xx,
                                                      const u16* __restrict__ wqkt,
                                                      u16* __restrict__ qk) {
    int w = threadIdx.x >> 6;          // 0..1
    int l = threadIdx.x & 63;
    int l15 = l & 15, g = l >> 4;
    int r0 = blockIdx.x * 32 + w * 16;

    f32x4 acc[8];
    #pragma unroll
    for (int i = 0; i < 8; ++i) acc[i] = (f32x4){0.f, 0.f, 0.f, 0.f};

    for (int kk = 0; kk < 16; ++kk) {
        int k = kk * 32 + g * 8;
        bf16x8 af = *(const bf16x8*)(xx + (size_t)(r0 + l15) * CC + k);
        #pragma unroll
        for (int Nt = 0; Nt < 8; ++Nt) {
            int c = Nt * 16 + l15;
            bf16x8 bfr = *(const bf16x8*)(wqkt + c * CC + k);
            acc[Nt] = __builtin_amdgcn_mfma_f32_16x16x32_bf16(af, bfr, acc[Nt], 0, 0, 0);
        }
    }
    #pragma unroll
    for (int Nt = 0; Nt < 8; ++Nt) {
        int c = Nt * 16 + l15;
        float scl = (c < 64) ? 0.125f : 1.0f;
        #pragma unroll
        for (int jj = 0; jj < 4; ++jj) {
            int rg = r0 + g * 4 + jj;
            qk[rg * 128 + c] = f2bf(acc[Nt][jj] * scl);
        }
    }
}

// ---------- Kernel 3: vT = (x_emb @ Wv)^T -> vt bf16 [512][T] ----------
__global__ __launch_bounds__(256) void v_gemm_kernel(const float* __restrict__ xe,
                                                     const u16* __restrict__ wvt,
                                                     u16* __restrict__ vt) {
    int w = threadIdx.x >> 6;
    int l = threadIdx.x & 63;
    int l15 = l & 15, g = l >> 4;
    int bm = blockIdx.x >> 2, bn = blockIdx.x & 3;
    int r0 = bm * 64 + w * 16;
    int c0 = bn * 128;

    f32x4 acc[8];
    #pragma unroll
    for (int i = 0; i < 8; ++i) acc[i] = (f32x4){0.f, 0.f, 0.f, 0.f};

    for (int kk = 0; kk < 16; ++kk) {
        int k = kk * 32 + g * 8;
        const float4* ap = (const float4*)(xe + (size_t)(r0 + l15) * CC + k);
        float4 a1 = ap[0], a2 = ap[1];
        bf16x8 af;
        af[0] = (short)f2bf(a1.x); af[1] = (short)f2bf(a1.y);
        af[2] = (short)f2bf(a1.z); af[3] = (short)f2bf(a1.w);
        af[4] = (short)f2bf(a2.x); af[5] = (short)f2bf(a2.y);
        af[6] = (short)f2bf(a2.z); af[7] = (short)f2bf(a2.w);
        #pragma unroll
        for (int Nt = 0; Nt < 8; ++Nt) {
            int c = c0 + Nt * 16 + l15;
            bf16x8 bfr = *(const bf16x8*)(wvt + c * CC + k);
            acc[Nt] = __builtin_amdgcn_mfma_f32_16x16x32_bf16(af, bfr, acc[Nt], 0, 0, 0);
        }
    }
    #pragma unroll
    for (int Nt = 0; Nt < 8; ++Nt) {
        int c = c0 + Nt * 16 + l15;
        s16x4 o4;
        o4[0] = (short)f2bf(acc[Nt][0]);
        o4[1] = (short)f2bf(acc[Nt][1]);
        o4[2] = (short)f2bf(acc[Nt][2]);
        o4[3] = (short)f2bf(acc[Nt][3]);
        *(s16x4*)(vt + (size_t)c * TT + r0 + g * 4) = o4;
    }
}

// ---------- Kernel 4: flash, BM=128, 16 waves (64x64/wave, 64 acc regs), async dbuf ----------
__global__ __launch_bounds__(1024, 4) void flash_kernel(const u16* __restrict__ qk,
                                                        const u16* __restrict__ vt,
                                                        const float* __restrict__ x,
                                                        float* __restrict__ part,
                                                        float* __restrict__ out,
                                                        int CT) {
    extern __shared__ u16 smem[];
    u16* const Klds = smem;            // [64 s][8 slots of 8 bf16], swizzled, 8KB
    u16* const Slds = smem + 4096;     // [128 r][64 s], XOR-swizzled 16B slots, 16KB
    u16* const Vb0  = smem + 12288;    // 2 x [512 c][64 s], source-swizzled, 2x64KB

    const int tid = threadIdx.x;
    const int w = tid >> 6, l = tid & 63;
    const int l15 = l & 15, g = l >> 4;
    const int wr = w >> 3, wcol = w & 7;     // PV: out rows wr*64, cols wcol*64
    const int mt = w >> 1, half = w & 1;     // QK^T: S rows mt*16, cols half*32

    // decode blockIdx -> (rt, ch)
    int b2 = (int)blockIdx.x, rt = 0, base = 0;
    for (;;) {
        int nt_ = 2 * rt + 2, nc_ = (nt_ + CT - 1) / CT;
        if (b2 < base + nc_) break;
        base += nc_; ++rt;
    }
    const int nt = 2 * rt + 2, nc = (nt + CT - 1) / CT, ch = b2 - base;
    const int t_lo = ch * nt / nc, t_hi = (ch + 1) * nt / nc;

    // Q fragments for this wave's QK^T rows (mt*16..+16), pre-scaled by 1/8
    const int qrow = rt * 128 + mt * 16 + l15;
    const bf16x8 qs0 = *(const bf16x8*)(qk + (size_t)qrow * 128 + g * 8);
    const bf16x8 qs1 = *(const bf16x8*)(qk + (size_t)qrow * 128 + 32 + g * 8);

    f32x4 acc[4][4];
    #pragma unroll
    for (int m = 0; m < 4; ++m)
        #pragma unroll
        for (int n = 0; n < 4; ++n) acc[m][n] = (f32x4){0.f, 0.f, 0.f, 0.f};

    const int sIk = tid >> 3;          // K stage row (tid<512)
    const int pk = tid & 7;
    const int vrow = w * 8 + (l >> 3); // V stage: row c = i*128 + vrow
    const int pv = l & 7;

    int cur = 0;

    // prologue: K(t_lo) reg + V(t_lo) DMA -> buf0, then K reg->LDS
    bf16x8 k0;
    if (tid < 512)
        k0 = *(const bf16x8*)(qk + (size_t)(t_lo * 64 + sIk) * 128 + 64 + ((pk ^ (sIk & 7)) << 3));
    #pragma unroll
    for (int i = 0; i < 4; ++i) {
        int c = i * 128 + vrow;
        gld16(vt + (size_t)c * TT + t_lo * 64 + ((pv ^ (c & 7)) << 3),
              Vb0 + i * 8192 + w * 512 + l * 8);
    }
    if (tid < 512) *(bf16x8*)&Klds[sIk * 64 + pk * 8] = k0;
    LGKM0();
    __builtin_amdgcn_s_barrier();

    for (int j = t_lo; j < t_hi; ++j) {
        const int s0 = j * 64;
        const bool more = (j + 1 < t_hi);

        bf16x8 knext;
        if (more) {
            if (tid < 512)
                knext = *(const bf16x8*)(qk + (size_t)((j + 1) * 64 + sIk) * 128 + 64 + ((pk ^ (sIk & 7)) << 3));
            u16* vdst = Vb0 + (cur ^ 1) * 32768;
            #pragma unroll
            for (int i = 0; i < 4; ++i) {
                int c = i * 128 + vrow;
                gld16(vt + (size_t)c * TT + s0 + 64 + ((pv ^ (c & 7)) << 3),
                      vdst + i * 8192 + w * 512 + l * 8);
            }
        }

        // QK^T: wave computes S[mt*16..+16][half*32..+32] (4 MFMA)
        f32x4 sacc[2];
        sacc[0] = (f32x4){0.f, 0.f, 0.f, 0.f};
        sacc[1] = (f32x4){0.f, 0.f, 0.f, 0.f};
        #pragma unroll
        for (int t = 0; t < 2; ++t) {
            int srow = half * 32 + t * 16 + l15;
            #pragma unroll
            for (int ka = 0; ka < 2; ++ka) {
                int sl = (ka * 4 + g) ^ (srow & 7);
                bf16x8 kf = *(const bf16x8*)&Klds[srow * 64 + sl * 8];
                sacc[t] = __builtin_amdgcn_mfma_f32_16x16x32_bf16(
                    ka ? qs1 : qs0, kf, sacc[t], 0, 0, 0);
            }
        }

        // mask + convert + S -> LDS (swizzled)
        const bool diag = (j >= 2 * rt);
        #pragma unroll
        for (int t = 0; t < 2; ++t) {
            int scol = half * 32 + t * 16 + l15;
            #pragma unroll
            for (int jj = 0; jj < 4; ++jj) {
                int row = mt * 16 + g * 4 + jj;
                float val = sacc[t][jj];
                if (diag && (s0 + scol) > rt * 128 + row) val = 0.f;
                Slds[row * 64 + ((((scol >> 3) ^ (row & 7)) << 3) + (scol & 7))] = f2bf(val);
            }
        }

        // V(j) arrived; keep this iter's (5 / 4) ops in flight
        if (more) { if (w < 8) { VMCNT(5); } else { VMCNT(4); } } else { VMCNT(0); }
        LGKM0();
        __builtin_amdgcn_s_barrier();

        // K(j+1) reg -> LDS, hidden under PV
        if (more && tid < 512) *(bf16x8*)&Klds[sIk * 64 + pk * 8] = knext;

        // PV: A = S rows [wr*64,+64), B = V cols [wcol*64,+64) (32 MFMA)
        const u16* Vl = Vb0 + cur * 32768;
        __builtin_amdgcn_s_setprio(1);
        #pragma unroll
        for (int ka = 0; ka < 2; ++ka) {
            bf16x8 sf[4], vf[4];
            #pragma unroll
            for (int Mt = 0; Mt < 4; ++Mt) {
                int row = wr * 64 + Mt * 16 + l15;
                int sl = (ka * 4 + g) ^ (row & 7);
                sf[Mt] = *(const bf16x8*)&Slds[row * 64 + sl * 8];
            }
            #pragma unroll
            for (int Nt = 0; Nt < 4; ++Nt) {
                int cv = wcol * 64 + Nt * 16 + l15;
                int ph = (ka * 4 + g) ^ (cv & 7);
                vf[Nt] = *(const bf16x8*)&Vl[cv * 64 + ph * 8];
            }
            #pragma unroll
            for (int Nt = 0; Nt < 4; ++Nt)
                #pragma unroll
                for (int Mt = 0; Mt < 4; ++Mt)
                    acc[Mt][Nt] = __builtin_amdgcn_mfma_f32_16x16x32_bf16(
                        sf[Mt], vf[Nt], acc[Mt][Nt], 0, 0, 0);
        }
        __builtin_amdgcn_s_setprio(0);

        LGKM0();
        __builtin_amdgcn_s_barrier();
        cur ^= 1;
    }

    // epilogue: fold x in ch==0; direct out when nc==1, else partial slot
    const size_t obase = (size_t)(rt * 128) * 512;
    float* pb = part + (size_t)b2 * 65536;
    #pragma unroll
    for (int Mt = 0; Mt < 4; ++Mt) {
        #pragma unroll
        for (int Nt = 0; Nt < 4; ++Nt) {
            int col = wcol * 64 + Nt * 16 + l15;
            #pragma unroll
            for (int jj = 0; jj < 4; ++jj) {
                int row = wr * 64 + Mt * 16 + g * 4 + jj;
                float v = acc[Mt][Nt][jj];
                if (ch == 0) v += x[obase + (size_t)row * 512 + col];
                if (nc == 1) out[obase + (size_t)row * 512 + col] = v;
                else pb[row * 512 + col] = v;
            }
        }
    }
}

// ---------- Kernel 5: out = sum(partial chunks) for row-tiles with nc >= 2 ----------
__global__ void combine_kernel(const float* __restrict__ part,
                               float* __restrict__ out, int CT) {
    int i = blockIdx.x * 256 + threadIdx.x;   // float4 index, 1048576 total
    int row = i >> 7;
    int rt = row >> 7;
    int nc = (2 * rt + 2 + CT - 1) / CT;
    if (nc < 2) return;                       // flash wrote these rows directly
    int base = 0;
    for (int r = 0; r < rt; ++r) base += (2 * r + 2 + CT - 1) / CT;
    int rloc = row & 127;
    int c4 = i & 127;
    float4 v = {0.f, 0.f, 0.f, 0.f};
    for (int s = 0; s < nc; ++s) {
        const float4* p4 = (const float4*)(part + (size_t)(base + s) * 65536);
        float4 p = p4[rloc * 128 + c4];
        v.x += p.x; v.y += p.y; v.z += p.z; v.w += p.w;
    }
    ((float4*)out)[i] = v;
}

extern "C" void kernel_launch(void* const* d_in, const int* in_sizes, int n_in,
                              void* d_out, int out_size, void* d_ws, size_t ws_size,
                              hipStream_t stream) {
    (void)in_sizes; (void)n_in; (void)out_size;
    const float* x    = (const float*)d_in[0];
    const float* xe   = (const float*)d_in[1];
    const float* lns  = (const float*)d_in[2];
    const float* lnb  = (const float*)d_in[3];
    const float* Wq   = (const float*)d_in[4];
    const float* Wk   = (const float*)d_in[5];
    const float* Wv   = (const float*)d_in[6];
    float* out = (float*)d_out;
    char* ws = (char*)d_ws;

    size_t off_xx   = 0;                                   // bf16 [8192][512]  8 MB
    size_t off_qk   = off_xx   + (size_t)TT * CC * 2;      // bf16 [8192][128]  2 MB
    size_t off_wqkt = off_qk   + (size_t)TT * 128 * 2;     // bf16 [128][512]
    size_t off_wvt  = off_wqkt + (size_t)128 * 512 * 2;    // bf16 [512][512]
    size_t off_vt   = off_wvt  + (size_t)512 * 512 * 2;    // bf16 [512][8192]  8 MB
    size_t off_part = off_vt   + (size_t)TT * CC * 2;      // f32 slots x 256 KB

    // smallest CT with slots <= 256 and partials fitting ws
    int CT = 2, slots = 0;
    for (;;) {
        slots = 0;
        for (int rt = 0; rt < 64; ++rt) slots += (2 * rt + 2 + CT - 1) / CT;
        if ((slots <= 256 && off_part + (size_t)slots * 65536 * 4 <= ws_size) || CT >= 256) break;
        ++CT;
    }

    u16* xx   = (u16*)(ws + off_xx);
    u16* qk   = (u16*)(ws + off_qk);
    u16* wqkt = (u16*)(ws + off_wqkt);
    u16* wvt  = (u16*)(ws + off_wvt);
    u16* vt   = (u16*)(ws + off_vt);
    float* part = (float*)(ws + off_part);

    const size_t flash_lds = (size_t)(4096 + 8192 + 2 * 32768) * sizeof(u16);  // 152 KB

    hipLaunchKernelGGL(lnw_kernel,     dim3(3328), dim3(256), 0, stream,
                       x, lns, lnb, Wq, Wk, Wv, xx, wqkt, wvt);
    hipLaunchKernelGGL(qk_gemm_kernel, dim3(256),  dim3(128), 0, stream, xx, wqkt, qk);
    hipLaunchKernelGGL(v_gemm_kernel,  dim3(512),  dim3(256), 0, stream, xe, wvt, vt);
    hipLaunchKernelGGL(flash_kernel,   dim3(slots), dim3(1024), flash_lds, stream,
                       qk, vt, x, part, out, CT);
    hipLaunchKernelGGL(combine_kernel, dim3(4096), dim3(256), 0, stream, part, out, CT);
}